// Round 1
// baseline (138.928 us; speedup 1.0000x reference)
//
#include <hip/hip_runtime.h>
#include <stdint.h>

#define B_    8
#define N_    512
#define DIN   1024
#define DOUT  1024
#define L_    16
#define T_    4096

#define BM 128
#define BN 128
#define BK 64
#define NB (DOUT / BN)          /* 8 */
#define MT_MAX 272              /* sum ceil(cnt_l*8/128) <= 4096*8/128 + 16 */
#define ZROW ((long)B_ * N_)    /* zero-row index in pooled_bf16 */

typedef __attribute__((ext_vector_type(8))) short short8;
typedef __attribute__((ext_vector_type(4))) float f32x4;

/* ---- workspace layout (bytes) ----
   [0, WS_W)        pooled_bf16: B*N*DIN + one zero row     (8,392,704 B)
   [WS_W, WS_META)  W_bf16:      L*DOUT*DIN                 (33,554,432 B)
   [WS_META, ...)   int meta:
      [0, T)            map:   n | lidx<<16   (invalid: n=0xFFFF, lidx=15)
      [T, 2T)           tlist: t | n<<16      (grouped by lidx)
      [2T, 2T+16)       goff   (t-list offset per l)
      [2T+16, 2T+32)    grows  (rows per group = cnt*8)
      [2T+32, +MT_MAX)  table: l | row0<<4
      [2T+32+MT_MAX]    ntiles
*/
#define POOLED_ELEMS ((long)B_ * N_ * DIN + DIN)
#define WS_W_OFF     ((size_t)POOLED_ELEMS * 2)
#define WS_META_OFF  (WS_W_OFF + (size_t)L_ * DOUT * DIN * 2)

__device__ __forceinline__ unsigned short f2bf(float f) {
  unsigned u = __float_as_uint(f);
  u += 0x7FFFu + ((u >> 16) & 1u);   /* RNE */
  return (unsigned short)(u >> 16);
}

__device__ __forceinline__ void gload_lds16(const void* g, void* l) {
  __builtin_amdgcn_global_load_lds(
      (const __attribute__((address_space(1))) void*)g,
      (__attribute__((address_space(3))) void*)l, 16, 0, 0);
}

/* ---------------- kernel 1: fp32 -> bf16 conversion ---------------- */
__global__ void k_convert(const float* __restrict__ pooled,
                          const float* __restrict__ W,
                          unsigned short* __restrict__ wsP,
                          unsigned short* __restrict__ wsW) {
  const long np4 = (long)B_ * N_ * DIN / 4;     /* 1,048,576 */
  const long nw4 = (long)L_ * DOUT * DIN / 4;   /* 4,194,304 */
  const long nz4 = DIN / 4;                     /* zero row chunks */
  long i = (long)blockIdx.x * blockDim.x + threadIdx.x;
  const long stride = (long)gridDim.x * blockDim.x;
  for (; i < np4 + nw4 + nz4; i += stride) {
    if (i < np4) {
      float4 v = ((const float4*)pooled)[i];
      ushort4 o = { f2bf(v.x), f2bf(v.y), f2bf(v.z), f2bf(v.w) };
      ((ushort4*)wsP)[i] = o;
    } else if (i < np4 + nw4) {
      float4 v = ((const float4*)W)[i - np4];
      ushort4 o = { f2bf(v.x), f2bf(v.y), f2bf(v.z), f2bf(v.w) };
      ((ushort4*)wsW)[i - np4] = o;
    } else {
      ushort4 z = {0, 0, 0, 0};
      ((ushort4*)wsP)[i - nw4] = z;              /* zero row */
    }
  }
}

/* ---------------- kernel 2: per-t (seg, lidx) map ---------------- */
__global__ void k_map(const int* __restrict__ pidx, int* __restrict__ map) {
  int t = blockIdx.x * blockDim.x + threadIdx.x;
  if (t >= T_) return;
  /* searchsorted left: first i with pidx[i] >= t */
  int lo = 0, hi = N_;
  while (lo < hi) {
    int mid = (lo + hi) >> 1;
    if (pidx[mid] < t) lo = mid + 1; else hi = mid;
  }
  int n, lidx;
  if (lo < N_) {
    int start = (lo > 0) ? (pidx[lo - 1] + 1) : 0;
    int li = t - start;
    lidx = li > (L_ - 1) ? (L_ - 1) : li;
    n = lo;
  } else {          /* invalid: route through zero row */
    n = 0xFFFF;
    lidx = L_ - 1;
  }
  map[t] = n | (lidx << 16);
}

/* ---------------- kernel 3: group by lidx + tile table ---------------- */
__global__ void k_group(const int* __restrict__ map,
                        unsigned* __restrict__ tlist,
                        int* __restrict__ goff, int* __restrict__ grows,
                        unsigned* __restrict__ table, int* __restrict__ ntiles) {
  __shared__ int cnt[L_];
  __shared__ int pos[L_];
  int tid = threadIdx.x;
  if (tid < L_) cnt[tid] = 0;
  __syncthreads();
  for (int t = tid; t < T_; t += 256)
    atomicAdd(&cnt[(map[t] >> 16) & 0xFFFF], 1);
  __syncthreads();
  if (tid == 0) {
    int off = 0;
    for (int l = 0; l < L_; ++l) {
      pos[l] = off; goff[l] = off; grows[l] = cnt[l] * B_;
      off += cnt[l];
    }
  }
  __syncthreads();
  for (int t = tid; t < T_; t += 256) {
    int m = map[t];
    int l = (m >> 16) & 0xFFFF;
    int p = atomicAdd(&pos[l], 1);
    tlist[p] = (unsigned)t | ((unsigned)(m & 0xFFFF) << 16);
  }
  __syncthreads();
  if (tid == 0) {
    int tt = 0;
    for (int l = 0; l < L_; ++l) {
      int rows = cnt[l] * B_;
      for (int r0 = 0; r0 < rows; r0 += BM)
        table[tt++] = (unsigned)l | ((unsigned)r0 << 4);
    }
    *ntiles = tt;
  }
}

/* ---------------- kernel 4: grouped gather-GEMM (bf16 MFMA) ----------------
   C[row, :] = A[row, :] (gathered pooled row, bf16) x W[l]^T
   tile: 128x128, BK=64, 4 waves (2x2), per-wave 4x4 frags of 16x16x32 MFMA */
__global__ void k_gemm(const unsigned short* __restrict__ wsP,
                       const unsigned short* __restrict__ wsW,
                       const unsigned* __restrict__ tlist,
                       const int* __restrict__ goff,
                       const int* __restrict__ grows,
                       const unsigned* __restrict__ table,
                       const int* __restrict__ ntiles,
                       float* __restrict__ out) {
  const int bid = blockIdx.x;
  const int mt = bid / NB;
  const int nt = bid % NB;
  if (mt >= *ntiles) return;

  const unsigned te = table[mt];
  const int l    = te & 15;
  const int row0 = (int)(te >> 4);
  const int toff = goff[l];
  const int rows = grows[l];

  __shared__ __align__(16) unsigned short As[BM * BK];   /* 16 KiB */
  __shared__ __align__(16) unsigned short Bs[BM * BK];   /* 16 KiB */

  const int tid  = threadIdx.x;
  const int w    = tid >> 6;
  const int lane = tid & 63;
  const int inoff = (lane & 7) * 16;          /* byte offset within 128B row */

  /* per-thread staging row pointers: rows r = i*32 + w*8 + (lane>>3) */
  const unsigned short* arow[4];
  const unsigned short* brow[4];
  const unsigned short* wbase = wsW + (long)l * DOUT * DIN + (long)nt * BN * DIN;
#pragma unroll
  for (int i = 0; i < 4; ++i) {
    int r  = i * 32 + w * 8 + (lane >> 3);
    int rg = row0 + r;
    long rowElem;
    if (rg < rows) {
      unsigned e = tlist[toff + (rg >> 3)];
      unsigned n = e >> 16;
      int b = rg & 7;
      rowElem = (n == 0xFFFFu) ? ZROW * DIN : ((long)(b * N_ + (int)n)) * DIN;
    } else {
      rowElem = ZROW * DIN;                    /* padding -> zero row */
    }
    arow[i] = wsP + rowElem;
    brow[i] = wbase + (long)r * DIN;
  }

  f32x4 acc[4][4];
#pragma unroll
  for (int m = 0; m < 4; ++m)
#pragma unroll
    for (int n = 0; n < 4; ++n)
      acc[m][n] = (f32x4){0.f, 0.f, 0.f, 0.f};

  const int wmRow = (w >> 1) * 64;
  const int wnCol = (w & 1) * 64;

  for (int ks = 0; ks < DIN / BK; ++ks) {      /* 16 K-steps */
    const int k0b = ks * BK * 2;               /* byte offset along K */
    __syncthreads();                           /* prev reads done before overwrite */
#pragma unroll
    for (int i = 0; i < 4; ++i)
      gload_lds16((const char*)arow[i] + k0b + inoff,
                  (char*)As + (i * 32 + w * 8) * (BK * 2));
#pragma unroll
    for (int i = 0; i < 4; ++i)
      gload_lds16((const char*)brow[i] + k0b + inoff,
                  (char*)Bs + (i * 32 + w * 8) * (BK * 2));
    __syncthreads();

#pragma unroll
    for (int ks2 = 0; ks2 < 2; ++ks2) {
      short8 af[4], bf[4];
      const int kb = ks2 * 32 + (lane >> 4) * 8;
#pragma unroll
      for (int m = 0; m < 4; ++m)
        af[m] = *(const short8*)(As + (wmRow + m * 16 + (lane & 15)) * BK + kb);
#pragma unroll
      for (int n = 0; n < 4; ++n)
        bf[n] = *(const short8*)(Bs + (wnCol + n * 16 + (lane & 15)) * BK + kb);
#pragma unroll
      for (int m = 0; m < 4; ++m)
#pragma unroll
        for (int n = 0; n < 4; ++n)
          acc[m][n] = __builtin_amdgcn_mfma_f32_16x16x32_bf16(
              af[m], bf[n], acc[m][n], 0, 0, 0);
    }
  }

  /* epilogue: C/D layout col = lane&15, row = (lane>>4)*4 + j */
#pragma unroll
  for (int m = 0; m < 4; ++m) {
#pragma unroll
    for (int j = 0; j < 4; ++j) {
      int rt = wmRow + m * 16 + (lane >> 4) * 4 + j;
      int rg = row0 + rt;
      if (rg >= rows) continue;
      unsigned e = tlist[toff + (rg >> 3)];
      int b = rg & 7;
      int t = (int)(e & 0xFFFFu);
      float* orow = out + ((long)b * T_ + t) * DOUT + nt * BN + wnCol + (lane & 15);
#pragma unroll
      for (int n = 0; n < 4; ++n)
        orow[n * 16] = acc[m][n][j];
    }
  }
}

/* ---------------- launch ---------------- */
extern "C" void kernel_launch(void* const* d_in, const int* in_sizes, int n_in,
                              void* d_out, int out_size, void* d_ws, size_t ws_size,
                              hipStream_t stream) {
  const float* pooled = (const float*)d_in[0];
  const float* W      = (const float*)d_in[1];
  const int*   pidx   = (const int*)d_in[2];
  /* d_in[3] = target_length (compile-time T_ = 4096) */
  float* out = (float*)d_out;

  char* ws = (char*)d_ws;
  unsigned short* wsP = (unsigned short*)(ws);
  unsigned short* wsW = (unsigned short*)(ws + WS_W_OFF);
  int* meta  = (int*)(ws + WS_META_OFF);
  int* map   = meta;
  unsigned* tlist = (unsigned*)(meta + T_);
  int* goff  = meta + 2 * T_;
  int* grows = meta + 2 * T_ + 16;
  unsigned* table = (unsigned*)(meta + 2 * T_ + 32);
  int* ntiles = meta + 2 * T_ + 32 + MT_MAX;

  k_convert<<<2048, 256, 0, stream>>>(pooled, W, wsP, wsW);
  k_map<<<(T_ + 255) / 256, 256, 0, stream>>>(pidx, map);
  k_group<<<1, 256, 0, stream>>>(map, tlist, goff, grows, table, ntiles);
  k_gemm<<<MT_MAX * NB, 256, 0, stream>>>(wsP, wsW, tlist, goff, grows, table,
                                          ntiles, out);
}